// Round 5
// baseline (54564.728 us; speedup 1.0000x reference)
//
#include <hip/hip_runtime.h>
#include <cmath>

// Problem dims (fixed by reference)
#define B_   128
#define T_   500
#define MEL_ 80
#define RED_ 2
#define D_   256   // decoder dim
#define E_   128   // encoder/prenet-out dim
#define PRE_ 256   // prenet hidden
#define L_   256   // encoder length
#define TPB  1024
// enc row stride: 266 ushorts = 133 dwords (odd) -> conflict-free row-per-lane b32 reads
#define ESTR  266
#define ESTRD 133

typedef __attribute__((ext_vector_type(8))) short bf16x8;  // 8 bf16 = 4 VGPRs
typedef __attribute__((ext_vector_type(4))) float f32x4;   // MFMA 16x16 accumulator

__device__ __forceinline__ float sigmoidf_(float x) { return 1.f / (1.f + expf(-x)); }
__device__ __forceinline__ float bflo(unsigned u) { return __uint_as_float(u << 16); }
__device__ __forceinline__ float bfhi(unsigned u) { return __uint_as_float(u & 0xFFFF0000u); }
__device__ __forceinline__ ushort f2bf(float f) {
    unsigned u = __float_as_uint(f);
    return (ushort)((u + 0x7FFFu + ((u >> 16) & 1u)) >> 16);
}

// global bf16 row . fp32 LDS vector (prenet / proj2 small matvecs)
__device__ __forceinline__ float dotbf(const ushort* __restrict__ wrow,
                                       const float* v, int k8) {
    const uint4* w = reinterpret_cast<const uint4*>(wrow);
    float s = 0.f;
#pragma unroll 8
    for (int k = 0; k < k8; ++k) {
        uint4 u = w[k];
        const float* vv = v + k * 8;
        s = fmaf(bflo(u.x), vv[0], s); s = fmaf(bfhi(u.x), vv[1], s);
        s = fmaf(bflo(u.y), vv[2], s); s = fmaf(bfhi(u.y), vv[3], s);
        s = fmaf(bflo(u.z), vv[4], s); s = fmaf(bfhi(u.z), vv[5], s);
        s = fmaf(bflo(u.w), vv[6], s); s = fmaf(bfhi(u.w), vv[7], s);
    }
    return s;
}

__global__ void cvt_bf16_kernel(const float* __restrict__ src,
                                ushort* __restrict__ dst, int n) {
    int i = blockIdx.x * blockDim.x + threadIdx.x;
    if (i < n) dst[i] = f2bf(src[i]);
}

// One wave computes y[rb*16 .. rb*16+15] = W[16 rows x K] @ x (bf16, fp32 acc) via
// a chained MFMA. A-frag: lane holds A[m=lane&15][k=quad*8+j] (16B global load).
// B-frag: column-broadcast of x (all 16 N-columns identical) from LDS bf16.
// D: col=lane&15, row=quad*4+reg -> col-0 lanes write the 16 results.
__device__ __forceinline__ void mfma_gate_chain(const ushort* __restrict__ W, int K,
                                                int rb, const ushort* xbf,
                                                float* out) {
    const int lane = threadIdx.x & 63;
    const int m = lane & 15, quad = lane >> 4;
    f32x4 acc = {0.f, 0.f, 0.f, 0.f};
    const ushort* arow = W + (size_t)(rb * 16 + m) * K + quad * 8;
    const int nkt = K >> 5;
#pragma unroll 8
    for (int kt = 0; kt < nkt; ++kt) {
        bf16x8 a = *(const bf16x8*)(const void*)(arow + kt * 32);
        bf16x8 bv = *(const bf16x8*)(const void*)(xbf + kt * 32 + quad * 8);
        acc = __builtin_amdgcn_mfma_f32_16x16x32_bf16(a, bv, acc, 0, 0, 0);
    }
    if (m == 0) {
#pragma unroll
        for (int r = 0; r < 4; ++r)
            out[rb * 16 + quad * 4 + r] = acc[r];
    }
}

__global__ __launch_bounds__(TPB) void decoder_mfma(
    const float* __restrict__ dec_input,   // [B,T,MEL] fp32
    const float* __restrict__ enc_output,  // [B,L,D]  fp32
    const ushort* __restrict__ pre_w1, const float* __restrict__ pre_b1,
    const ushort* __restrict__ pre_w2, const float* __restrict__ pre_b2,
    const ushort* __restrict__ attn_wih, const ushort* __restrict__ attn_whh,
    const float* __restrict__ attn_bih, const float* __restrict__ attn_bhh,
    const ushort* __restrict__ proj1_w, const float* __restrict__ proj1_b,
    const ushort* __restrict__ rnn1_wih, const ushort* __restrict__ rnn1_whh,
    const float* __restrict__ rnn1_bih, const float* __restrict__ rnn1_bhh,
    const ushort* __restrict__ rnn2_wih, const ushort* __restrict__ rnn2_whh,
    const float* __restrict__ rnn2_bih, const float* __restrict__ rnn2_bhh,
    const ushort* __restrict__ proj2_w, const float* __restrict__ proj2_b,
    float* __restrict__ mel_out,   // [B, T*RED, MEL]
    float* __restrict__ align_out) // [B, L, T]
{
    const int b    = blockIdx.x;
    const int tid  = threadIdx.x;
    const int lane = tid & 63;
    const int wv   = tid >> 6;

    __shared__ __align__(16) ushort s_enc[L_ * ESTR];   // 136192 B, bf16 enc[b]
    __shared__ __align__(16) float  A[2048];            // partials / gi (8 KB)
    __shared__ __align__(16) float  Bp[768];            // gh
    __shared__ __align__(16) float  s_frame[MEL_];
    __shared__ __align__(16) float  s_x1[PRE_];
    __shared__ __align__(16) ushort s_x_bf[E_];
    __shared__ __align__(16) float  s_ha[D_];
    __shared__ __align__(16) ushort s_ha_bf[D_];
    __shared__ __align__(16) float  s_h1[D_];
    __shared__ __align__(16) ushort s_h1_bf[D_];
    __shared__ __align__(16) float  s_h2[D_];
    __shared__ __align__(16) ushort s_h2_bf[D_];
    __shared__ __align__(16) float  s_dec[D_];
    __shared__ __align__(16) ushort s_dec_bf[D_];
    __shared__ __align__(16) float  s_y1[D_];
    __shared__ __align__(16) ushort s_y1_bf[D_];
    __shared__ __align__(16) float  s_y2[D_];
    __shared__ __align__(16) ushort s_cat_bf[2 * D_];
    __shared__ __align__(16) float  s_al[L_];
    __shared__ float s_pmax[4];
    __shared__ float s_psum[4];

    // ---- one-time: enc[b] fp32 -> bf16 LDS (odd-dword-stride rows) ----
    {
        const float4* eb = reinterpret_cast<const float4*>(enc_output + (size_t)b * L_ * D_);
        uint* dst = reinterpret_cast<uint*>(s_enc);
        for (int i = tid; i < (L_ * D_) / 4; i += TPB) {
            float4 f = eb[i];
            int row = i >> 6, c4 = i & 63;
            dst[row * ESTRD + 2 * c4]     = (unsigned)f2bf(f.x) | ((unsigned)f2bf(f.y) << 16);
            dst[row * ESTRD + 2 * c4 + 1] = (unsigned)f2bf(f.z) | ((unsigned)f2bf(f.w) << 16);
        }
    }
    if (tid < D_) {
        s_ha[tid] = 0.f; s_h1[tid] = 0.f; s_h2[tid] = 0.f;
        s_ha_bf[tid] = 0; s_h1_bf[tid] = 0; s_h2_bf[tid] = 0;
    }
    // preload frame 0
    if (tid < MEL_)
        s_frame[tid] = dec_input[(size_t)b * T_ * MEL_ + tid];
    __syncthreads();

    for (int t = 0; t < T_; ++t) {
        // P2: prenet1 (VALU): MEL->PRE
        if (tid < PRE_)
            s_x1[tid] = fmaxf(dotbf(pre_w1 + tid * MEL_, s_frame, MEL_ / 8) + pre_b1[tid], 0.f);
        __syncthreads();

        // P3: prenet2 partials: 128 rows, K=256 split 8-way
        {
            int p = tid >> 7, j = tid & 127;
            A[p * 128 + j] = dotbf(pre_w2 + j * PRE_ + p * 32, s_x1 + p * 32, 4);
        }
        __syncthreads();
        // P4: prenet2 combine -> x (bf16 only; consumed solely by attn wih MFMA)
        if (tid < E_) {
            float s = pre_b2[tid];
#pragma unroll
            for (int p = 0; p < 8; ++p) s += A[p * 128 + tid];
            s_x_bf[tid] = f2bf(fmaxf(s, 0.f));
        }
        __syncthreads();

        // P5: attn gates via MFMA: wih[768x128] (48 rb), whh[768x256] (48 rb)
        for (int c = wv; c < 96; c += 16) {
            if (c < 48) mfma_gate_chain(attn_wih, E_, c, s_x_bf, A);
            else        mfma_gate_chain(attn_whh, D_, c - 48, s_ha_bf, Bp);
        }
        __syncthreads();
        // P6: attn GRU combine
        if (tid < D_) {
            float gir = A[tid] + attn_bih[tid];
            float giz = A[D_ + tid] + attn_bih[D_ + tid];
            float gin = A[2 * D_ + tid] + attn_bih[2 * D_ + tid];
            float ghr = Bp[tid] + attn_bhh[tid];
            float ghz = Bp[D_ + tid] + attn_bhh[D_ + tid];
            float ghn = Bp[2 * D_ + tid] + attn_bhh[2 * D_ + tid];
            float r = sigmoidf_(gir + ghr);
            float z = sigmoidf_(giz + ghz);
            float n = tanhf(gin + r * ghn);
            float h = (1.f - z) * n + z * s_ha[tid];
            s_ha[tid] = h;
            s_ha_bf[tid] = f2bf(h);
        }
        __syncthreads();

        // P7: scores partials, 4-way K-split, b32 enc reads (conflict-free: odd stride)
        {
            int p = tid >> 8, l = tid & 255;
            const uint* erow = reinterpret_cast<const uint*>(s_enc) + l * ESTRD + p * 32;
            const float* hp = s_ha + p * 64;
            float sc = 0.f;
#pragma unroll
            for (int k = 0; k < 32; ++k) {
                uint u = erow[k];
                sc = fmaf(bflo(u), hp[2 * k], sc);
                sc = fmaf(bfhi(u), hp[2 * k + 1], sc);
            }
            A[p * 256 + l] = sc;
        }
        __syncthreads();
        float e = 0.f;
        // P8: finalize score + wave max
        {
            float sc = 0.f;
            if (tid < L_) {
                sc = A[tid] + A[256 + tid] + A[512 + tid] + A[768 + tid];
                float m = sc;
                for (int o = 32; o > 0; o >>= 1) m = fmaxf(m, __shfl_xor(m, o, 64));
                if (lane == 0) s_pmax[wv] = m;
            }
            __syncthreads();
            // P9: exp + wave sum (unnormalized alignment kept in s_al)
            if (tid < L_) {
                float mm = fmaxf(fmaxf(s_pmax[0], s_pmax[1]), fmaxf(s_pmax[2], s_pmax[3]));
                e = expf(sc - mm);
                s_al[tid] = e;
                float sm = e;
                for (int o = 32; o > 0; o >>= 1) sm += __shfl_xor(sm, o, 64);
                if (lane == 0) s_psum[wv] = sm;
            }
        }
        __syncthreads();

        // P10: ctx partials (unnormalized), 8-way L-split, uint d-pair reads.
        // 8 slices x 256 floats = A[0..2047] (A is 2048 -- overflow bug fixed).
        {
            int p = tid >> 7, j = tid & 127;
            const uint* ebase = reinterpret_cast<const uint*>(s_enc) + j;
            const float* alp = s_al + p * 32;
            float c0 = 0.f, c1 = 0.f;
#pragma unroll
            for (int l = 0; l < 32; ++l) {
                uint u = ebase[(p * 32 + l) * ESTRD];
                float al = alp[l];
                c0 = fmaf(bflo(u), al, c0);
                c1 = fmaf(bfhi(u), al, c1);
            }
            A[p * 256 + 2 * j]     = c0;
            A[p * 256 + 2 * j + 1] = c1;
        }
        __syncthreads();
        // P11: ctx combine over all 8 slices (normalize) -> cat_bf; write alignment
        if (tid < D_) {
            float denom = s_psum[0] + s_psum[1] + s_psum[2] + s_psum[3];
            float inv = 1.f / denom;
            float c = 0.f;
#pragma unroll
            for (int p = 0; p < 8; ++p) c += A[p * 256 + tid];
            c *= inv;
            s_cat_bf[tid]      = f2bf(c);
            s_cat_bf[D_ + tid] = f2bf(s_ha[tid]);
            align_out[((size_t)b * L_ + tid) * T_ + t] = s_al[tid] * inv;
        }
        __syncthreads();

        // P12: proj1 via MFMA: [256 x 512], one 16-row block per wave
        {
            const int m = lane & 15, quad = lane >> 4;
            f32x4 acc = {0.f, 0.f, 0.f, 0.f};
            const ushort* arow = proj1_w + (size_t)(wv * 16 + m) * (2 * D_) + quad * 8;
#pragma unroll
            for (int kt = 0; kt < 16; ++kt) {
                bf16x8 a = *(const bf16x8*)(const void*)(arow + kt * 32);
                bf16x8 bv = *(const bf16x8*)(const void*)(s_cat_bf + kt * 32 + quad * 8);
                acc = __builtin_amdgcn_mfma_f32_16x16x32_bf16(a, bv, acc, 0, 0, 0);
            }
            if (m == 0) {
#pragma unroll
                for (int r = 0; r < 4; ++r) {
                    int row = wv * 16 + quad * 4 + r;
                    float v = acc[r] + proj1_b[row];
                    s_dec[row] = v;
                    s_dec_bf[row] = f2bf(v);
                }
            }
        }
        __syncthreads();

        // P13: rnn1 gates via MFMA
        for (int c = wv; c < 96; c += 16) {
            if (c < 48) mfma_gate_chain(rnn1_wih, D_, c, s_dec_bf, A);
            else        mfma_gate_chain(rnn1_whh, D_, c - 48, s_h1_bf, Bp);
        }
        __syncthreads();
        // P14: rnn1 combine
        if (tid < D_) {
            float gir = A[tid] + rnn1_bih[tid];
            float giz = A[D_ + tid] + rnn1_bih[D_ + tid];
            float gin = A[2 * D_ + tid] + rnn1_bih[2 * D_ + tid];
            float ghr = Bp[tid] + rnn1_bhh[tid];
            float ghz = Bp[D_ + tid] + rnn1_bhh[D_ + tid];
            float ghn = Bp[2 * D_ + tid] + rnn1_bhh[2 * D_ + tid];
            float r = sigmoidf_(gir + ghr);
            float z = sigmoidf_(giz + ghz);
            float n = tanhf(gin + r * ghn);
            float h = (1.f - z) * n + z * s_h1[tid];
            s_h1[tid] = h; s_h1_bf[tid] = f2bf(h);
            float y = s_dec[tid] + h;
            s_y1[tid] = y; s_y1_bf[tid] = f2bf(y);
        }
        __syncthreads();

        // P15: rnn2 gates via MFMA
        for (int c = wv; c < 96; c += 16) {
            if (c < 48) mfma_gate_chain(rnn2_wih, D_, c, s_y1_bf, A);
            else        mfma_gate_chain(rnn2_whh, D_, c - 48, s_h2_bf, Bp);
        }
        __syncthreads();
        // P16: rnn2 combine
        if (tid < D_) {
            float gir = A[tid] + rnn2_bih[tid];
            float giz = A[D_ + tid] + rnn2_bih[D_ + tid];
            float gin = A[2 * D_ + tid] + rnn2_bih[2 * D_ + tid];
            float ghr = Bp[tid] + rnn2_bhh[tid];
            float ghz = Bp[D_ + tid] + rnn2_bhh[D_ + tid];
            float ghn = Bp[2 * D_ + tid] + rnn2_bhh[2 * D_ + tid];
            float r = sigmoidf_(gir + ghr);
            float z = sigmoidf_(giz + ghz);
            float n = tanhf(gin + r * ghn);
            float h = (1.f - z) * n + z * s_h2[tid];
            s_h2[tid] = h; s_h2_bf[tid] = f2bf(h);
            s_y2[tid] = s_y1[tid] + h;
        }
        __syncthreads();

        // P17: proj2 partials (VALU, 640 tasks) + prefetch next frame (idle lanes)
        if (tid < 640) {
            int j = tid >> 2, p = tid & 3;
            A[tid] = dotbf(proj2_w + j * D_ + p * 64, s_y2 + p * 64, 8);
        } else if (tid >= 768 && tid < 768 + MEL_) {
            int tn = (t + 1 < T_) ? t + 1 : t;
            s_frame[tid - 768] = dec_input[((size_t)b * T_ + tn) * MEL_ + (tid - 768)];
        }
        __syncthreads();
        // P18: proj2 combine + mel store (A next written in P3, two barriers away)
        if (tid < MEL_ * RED_) {
            float s = A[4 * tid] + A[4 * tid + 1] + A[4 * tid + 2] + A[4 * tid + 3] + proj2_b[tid];
            mel_out[(size_t)b * (T_ * RED_ * MEL_) + (size_t)t * (MEL_ * RED_) + tid] = s;
        }
    }
}

extern "C" void kernel_launch(void* const* d_in, const int* in_sizes, int n_in,
                              void* d_out, int out_size, void* d_ws, size_t ws_size,
                              hipStream_t stream) {
    const float* dec_input = (const float*)d_in[0];
    const float* enc_output= (const float*)d_in[1];
    const float* pre_w1    = (const float*)d_in[2];
    const float* pre_b1    = (const float*)d_in[3];
    const float* pre_w2    = (const float*)d_in[4];
    const float* pre_b2    = (const float*)d_in[5];
    const float* attn_wih  = (const float*)d_in[6];
    const float* attn_whh  = (const float*)d_in[7];
    const float* attn_bih  = (const float*)d_in[8];
    const float* attn_bhh  = (const float*)d_in[9];
    const float* proj1_w   = (const float*)d_in[10];
    const float* proj1_b   = (const float*)d_in[11];
    const float* rnn1_wih  = (const float*)d_in[12];
    const float* rnn1_whh  = (const float*)d_in[13];
    const float* rnn1_bih  = (const float*)d_in[14];
    const float* rnn1_bhh  = (const float*)d_in[15];
    const float* rnn2_wih  = (const float*)d_in[16];
    const float* rnn2_whh  = (const float*)d_in[17];
    const float* rnn2_bih  = (const float*)d_in[18];
    const float* rnn2_bhh  = (const float*)d_in[19];
    const float* proj2_w   = (const float*)d_in[20];
    const float* proj2_b   = (const float*)d_in[21];

    float* mel   = (float*)d_out;
    float* align = (float*)d_out + (size_t)B_ * T_ * RED_ * MEL_;

    const int n_pre_w1   = PRE_ * MEL_;
    const int n_pre_w2   = E_ * PRE_;
    const int n_attn_wih = 3 * D_ * E_;
    const int n_attn_whh = 3 * D_ * D_;
    const int n_proj1    = D_ * 2 * D_;
    const int n_rnn_w    = 3 * D_ * D_;
    const int n_proj2    = MEL_ * RED_ * D_;

    ushort* w = (ushort*)d_ws;
    ushort* c_pre_w1   = w; w += n_pre_w1;
    ushort* c_pre_w2   = w; w += n_pre_w2;
    ushort* c_attn_wih = w; w += n_attn_wih;
    ushort* c_attn_whh = w; w += n_attn_whh;
    ushort* c_proj1    = w; w += n_proj1;
    ushort* c_rnn1_wih = w; w += n_rnn_w;
    ushort* c_rnn1_whh = w; w += n_rnn_w;
    ushort* c_rnn2_wih = w; w += n_rnn_w;
    ushort* c_rnn2_whh = w; w += n_rnn_w;
    ushort* c_proj2    = w; w += n_proj2;

    auto cvt = [&](const float* src, ushort* dst, int n) {
        cvt_bf16_kernel<<<dim3((n + 255) / 256), dim3(256), 0, stream>>>(src, dst, n);
    };
    cvt(pre_w1,   c_pre_w1,   n_pre_w1);
    cvt(pre_w2,   c_pre_w2,   n_pre_w2);
    cvt(attn_wih, c_attn_wih, n_attn_wih);
    cvt(attn_whh, c_attn_whh, n_attn_whh);
    cvt(proj1_w,  c_proj1,    n_proj1);
    cvt(rnn1_wih, c_rnn1_wih, n_rnn_w);
    cvt(rnn1_whh, c_rnn1_whh, n_rnn_w);
    cvt(rnn2_wih, c_rnn2_wih, n_rnn_w);
    cvt(rnn2_whh, c_rnn2_whh, n_rnn_w);
    cvt(proj2_w,  c_proj2,    n_proj2);

    decoder_mfma<<<dim3(B_), dim3(TPB), 0, stream>>>(
        dec_input, enc_output,
        c_pre_w1, pre_b1, c_pre_w2, pre_b2,
        c_attn_wih, c_attn_whh, attn_bih, attn_bhh,
        c_proj1, proj1_b,
        c_rnn1_wih, c_rnn1_whh, rnn1_bih, rnn1_bhh,
        c_rnn2_wih, c_rnn2_whh, rnn2_bih, rnn2_bhh,
        c_proj2, proj2_b,
        mel, align);
}